// Round 5
// baseline (16980.170 us; speedup 1.0000x reference)
//
#include <hip/hip_runtime.h>

// Autoregressive GRU decoder, persistent cooperative kernel.
// B=128, S=512, HID=1024, EMB=128, NL=32.
//
// Input dtype (fp32 vs bf16) detected on-device; OUTPUT FORMAT IS COUPLED
// to the detected input dtype (f32 -> float out, bf16 -> u16 bf16 out).
//
// Numerics (fp32 mode): W = Whi(bf16,LDS) + Wlo(bf16, device-global,
// precomputed); x and h split hi/lo bf16 in-register. All 4 limb products
// go through bf16 MFMA into one fp32 accumulator -> gate preactivations
// accurate to ~1.5e-6. G_lab in fp64. Logits from exact fp32 h_new held in
// registers, via DISTRIBUTED in-order fp32 partial dots (16 cols per h-WG,
// summed in strict rg order by x-WGs) -> canonical left-to-right fp32 dot.
//
// SYNC (this revision): ONE cross-WG hop on the step critical path.
//  - h-WG epilogue computes its 16-col logits partials from in-register
//    fp32 h_new and publishes them WITH the h stamp (same vmcnt drain).
//  - x-WG b: polls its half's 64 stamps, sums partials in rg order (fp32),
//    writes output logits row, argmax, publishes packed (it<<8)|pred to
//    its own padded word. This whole path is OFF the critical chain
//    (pred(it-1) overlaps gh-GEMM(it)).
//  - NO per-step fences at all: mutable cross-WG data (h limbs, partials,
//    stamps, pred words) uses RELAXED agent-scope atomics (LLC-coherent);
//    read-only data (weights, GIX, Glab, W_out) stays L2-resident.
//  - Double-buffered h by step parity closes WAR; per-row pred gating
//    closes the partial-buffer WAR (x-WG b reads partials(s) before
//    publishing pred(s); h threads overwrite row b's partials only after
//    observing pred(s)[b]).
//  Phase 0 precomputes GIX for all 512 steps (published once by
//  __threadfence + gridbar). Sentinels 999/555 self-test visibility.

#define S_    512
#define HID_  1024
#define EMB_  128
#define NL_   32
#define G3_   3072

#define LDS_A_STRIDE 1032                      // 1024 + 8 pad (bf16 elems)
#define LDS_A_BYTES  (48 * LDS_A_STRIDE * 2)   // 99072
#define CP_STRIDE    52                        // fp32 elems, pad 48->52
#define LDS_CP_BYTES (4 * 64 * CP_STRIDE * 4)  // 53248
#define LDS_WO_BYTES 2048                      // 32x16 f32 W_out slice
#define LDS_BYTES    (LDS_A_BYTES + LDS_CP_BYTES + LDS_WO_BYTES) // 154368

typedef __attribute__((ext_vector_type(8))) short          short8;
typedef __attribute__((ext_vector_type(8))) unsigned short u16x8;
typedef __attribute__((ext_vector_type(4))) unsigned short u16x4;
typedef __attribute__((ext_vector_type(4))) float          f32x4;
typedef unsigned long long u64_t;

// ---------------- device-global state (no d_ws dependence) ---------------
__device__ unsigned int   g_ctr[576];           // 8 groups @ +g*64, root @ +512
__device__ unsigned int   g_flag[1];
__device__ unsigned int   g_vis[256];
__device__ unsigned int   g_hseq[2][64 * 16];   // [half][rg*16], line-padded
__device__ unsigned int   g_predw[128 * 16];    // [b*16]: (it<<8)|pred
__device__ unsigned short g_hhi[2][128 * HID_]; // double-buffered by parity
__device__ unsigned short g_hlo[2][128 * HID_];
__device__ float          g_lp[64 * 128 * 32];  // logits partials [rg][b][l]
__device__ float          g_Glab[NL_ * G3_];    // b_ih folded in
__device__ unsigned short g_Wlox[G3_ * HID_];   // lo limb of W_ih x-part
__device__ unsigned short g_Wlohh[G3_ * HID_];  // lo limb of W_hh
// GIX for all steps: [it][slot][bl][48] -- 512*128*64*48 fp32 = 805 MB BSS.
__device__ float          g_GIXall[(size_t)S_ * 128 * 64 * 48];

__device__ __forceinline__ float bf2f(unsigned short u) {
  union { unsigned int i; float f; } v; v.i = ((unsigned int)u) << 16; return v.f;
}
__device__ __forceinline__ unsigned short f2bf(float f) {
  union { float f; unsigned int i; } v; v.f = f;
  unsigned int u = v.i;
  return (unsigned short)((u + 0x7FFFu + ((u >> 16) & 1u)) >> 16);
}
__device__ __forceinline__ short8 ld_bf8(const unsigned short* p) {
  return __builtin_bit_cast(short8, *(const u16x8*)p);
}
__device__ __forceinline__ float ldin(const void* p, long i, int f32) {
  return f32 ? ((const float*)p)[i] : bf2f(((const unsigned short*)p)[i]);
}
__device__ __forceinline__ void store_out(void* out, int f32, long idx, float v) {
  if (f32) ((float*)out)[idx] = v;
  else     ((unsigned short*)out)[idx] = f2bf(v);
}

// ---- LLC-coherent helpers: relaxed agent atomics (sc0|sc1), no fences ----
__device__ __forceinline__ u64_t ald64(const void* p) {
  return __hip_atomic_load((const u64_t*)p, __ATOMIC_RELAXED,
                           __HIP_MEMORY_SCOPE_AGENT);
}
__device__ __forceinline__ void ast64(void* p, u64_t v) {
  __hip_atomic_store((u64_t*)p, v, __ATOMIC_RELAXED,
                     __HIP_MEMORY_SCOPE_AGENT);
}
__device__ __forceinline__ unsigned int ald32(const unsigned int* p) {
  return __hip_atomic_load(p, __ATOMIC_RELAXED, __HIP_MEMORY_SCOPE_AGENT);
}
__device__ __forceinline__ float aldf(const float* p) {
  union { unsigned int u; float f; } v;
  v.u = __hip_atomic_load((const unsigned int*)p, __ATOMIC_RELAXED,
                          __HIP_MEMORY_SCOPE_AGENT);
  return v.f;
}
__device__ __forceinline__ void ast32(unsigned int* p, unsigned int v) {
  __hip_atomic_store(p, v, __ATOMIC_RELAXED, __HIP_MEMORY_SCOPE_AGENT);
}
__device__ __forceinline__ short8 ld_bf8_coh(const unsigned short* p) {
  union { u64_t q[2]; short8 s; } u;
  u.q[0] = ald64(p);
  u.q[1] = ald64(p + 4);
  return u.s;
}
__device__ __forceinline__ void st_h4_coh(unsigned short* p, u16x4 v) {
  union { u16x4 h; u64_t q; } u; u.h = v;
  ast64(p, u.q);
}
__device__ __forceinline__ void st_f2_coh(float* p, float a, float b) {
  union { float f[2]; u64_t q; } u; u.f[0] = a; u.f[1] = b;
  ast64(p, u.q);
}

// ---- zero state each launch ----
__global__ void k_zero() {
  int t = blockIdx.x * 256 + threadIdx.x;       // 65536 threads
  if (t < 576) g_ctr[t] = 0u;
  else if (t < 832) g_vis[t - 576] = 0u;
  if (t >= 2048 && t < 4096) ((unsigned int*)g_hseq)[t - 2048] = 0u;
  if (t >= 4096 && t < 6144) g_predw[t - 4096] = 0u;
  const u16x4 z4 = {0, 0, 0, 0};
  for (int i = t; i < 2 * 128 * HID_ / 4; i += 65536) {
    ((u16x4*)g_hhi)[i] = z4;
    ((u16x4*)g_hlo)[i] = z4;
  }
}

// ---- dtype detector: bf16 W_ih bounded by 1/32; fp32 misread blows up ----
__global__ void k_detect(const unsigned short* __restrict__ W) {
  unsigned bad = 0;
  for (int i = threadIdx.x; i < 1024; i += 64) {
    float v = bf2f(W[i]);
    if (!(v * v <= 1.0f)) bad = 1;   // catches |v|>1 and NaN
  }
  unsigned long long b = __ballot(bad != 0);
  if (threadIdx.x == 0) g_flag[0] = (b != 0ull) ? 1u : 0u;
}

// ---- prep: G_lab[l][n] = b_ih[n] + sum_e emb[l][e]*W_ih[n][1024+e] (fp64) --
__global__ void k_prep(const void* __restrict__ emb,
                       const void* __restrict__ W_ih,
                       const void* __restrict__ b_ih) {
  const int f32 = (int)g_flag[0];
  int l = blockIdx.x / 12;
  int n = (blockIdx.x % 12) * 256 + threadIdx.x;
  double acc = (double)ldin(b_ih, n, f32);
  for (int e = 0; e < EMB_; ++e)
    acc += (double)ldin(emb, (long)l * EMB_ + e, f32) *
           (double)ldin(W_ih, (long)n * (HID_ + EMB_) + HID_ + e, f32);
  g_Glab[l * G3_ + n] = (float)acc;
}

// ---- prep: lo limbs of W (fp32 mode only) ----
__global__ void k_prepw(const void* __restrict__ W_ih,
                        const void* __restrict__ W_hh) {
  if (!g_flag[0]) return;
  long i4 = ((long)blockIdx.x * 256 + threadIdx.x) * 4;  // 3072 blocks
  if (i4 >= (long)G3_ * HID_) return;
  int row = (int)(i4 >> 10), col = (int)(i4 & 1023);
  f32x4 wh = *(const f32x4*)&((const float*)W_hh)[(long)row * HID_ + col];
  f32x4 wx = *(const f32x4*)&((const float*)W_ih)[(long)row * (HID_ + EMB_) + col];
  u16x4 lh, lx;
  #pragma unroll
  for (int j = 0; j < 4; ++j) {
    unsigned short h1 = f2bf(wh[j]);
    lh[j] = f2bf(wh[j] - bf2f(h1));
    unsigned short x1 = f2bf(wx[j]);
    lx[j] = f2bf(wx[j] - bf2f(x1));
  }
  *(u16x4*)&g_Wlohh[i4] = lh;
  *(u16x4*)&g_Wlox[i4]  = lx;
}

// ---- 2-level device barrier (startup/phase-0 only; not in steady loop) ----
__device__ __forceinline__ void gridbar(int wg, int bar) {
  __syncthreads();
  if (threadIdx.x == 0) {
    asm volatile("s_waitcnt vmcnt(0)" ::: "memory");
    unsigned int* c1   = g_ctr + (wg & 7) * 64;
    unsigned int* root = g_ctr + 512;
    unsigned int old = __hip_atomic_fetch_add(c1, 1u, __ATOMIC_RELAXED,
                                              __HIP_MEMORY_SCOPE_AGENT);
    if (old == 32u * (unsigned)(bar + 1) - 1u)
      __hip_atomic_fetch_add(root, 1u, __ATOMIC_RELAXED,
                             __HIP_MEMORY_SCOPE_AGENT);
    unsigned int tgt = 8u * (unsigned)(bar + 1);
    while (__hip_atomic_load(root, __ATOMIC_RELAXED,
                             __HIP_MEMORY_SCOPE_AGENT) < tgt)
      __builtin_amdgcn_s_sleep(1);
  }
  __syncthreads();
}

// ---- wait until all 64 producers of `half` stamped >= it (no fences) ----
__device__ __forceinline__ void wait_hseq(int half, int it) {
  if (threadIdx.x < 64) {
    const unsigned int* p = &g_hseq[half][threadIdx.x * 16];
    while ((int)ald32(p) < it) { }
  }
  __builtin_amdgcn_sched_barrier(0);
  __syncthreads();
}

// ---- stage 48-row hi-limb weight slice (rows [r16][z16][n16] of group rg) --
__device__ __forceinline__ void stage_w(unsigned short* sA, const void* Wsrc,
                                        int wstride, int rg, int f32, int tid) {
  if (f32) {
    const float* Ws = (const float*)Wsrc;
    for (int i = tid; i < 48 * 1024 / 4; i += 256) {
      int e = i * 4, row = e >> 10, k4 = e & 1023;
      int grow = (row >> 4) * HID_ + rg * 16 + (row & 15);
      f32x4 v = *(const f32x4*)&Ws[(long)grow * wstride + k4];
      u16x4 o;
      #pragma unroll
      for (int j = 0; j < 4; ++j) o[j] = f2bf(v[j]);
      *(u16x4*)&sA[row * LDS_A_STRIDE + k4] = o;
    }
  } else {
    const unsigned short* Ws = (const unsigned short*)Wsrc;
    for (int i = tid; i < 48 * 1024 / 4; i += 256) {
      int e = i * 4, row = e >> 10, k4 = e & 1023;
      int grow = (row >> 4) * HID_ + rg * 16 + (row & 15);
      *(u16x4*)&sA[row * LDS_A_STRIDE + k4] =
          *(const u16x4*)&Ws[(long)grow * wstride + k4];
    }
  }
}

// ---- main persistent kernel ----
__global__ __launch_bounds__(256) void k_seq(
    const void* __restrict__ hs,
    const void* __restrict__ W_ih,
    const void* __restrict__ W_hh,
    const void* __restrict__ b_hh,
    const void* __restrict__ W_out,
    const void* __restrict__ b_out,
    void* __restrict__ out) {
  extern __shared__ char smem[];
  unsigned short* sA  = (unsigned short*)smem;
  float*          sCp = (float*)(smem + LDS_A_BYTES);
  float*          sWo = (float*)(smem + LDS_A_BYTES + LDS_CP_BYTES);

  const int f32 = (int)g_flag[0];
  const int tid = threadIdx.x;
  const int wg  = blockIdx.x;
  const bool isx = (wg < 128);
  const int lid  = isx ? wg : wg - 128;
  const int rg = lid >> 1, bg = lid & 1;
  const int slot = lid;                 // (rg,bg) slot
  const int lane = tid & 63, wv = tid >> 6;
  const int m = lane & 15, q = lane >> 4;
  const int bl = tid & 63;              // epilogue local batch
  const int jj = (tid >> 6) * 4;        // epilogue local j base
  const int kw0 = wv * 256 + q * 8;

  int bar = 0;

  // ---- visibility self-test (probe barrier, bar 0) ----
  if (tid == 0) ast32(&g_vis[wg], (unsigned)wg + 1u);
  gridbar(wg, bar); ++bar;
  if (tid == 0) {
    unsigned p = ((unsigned)wg + 37u) & 255u;
    if (ald32(&g_vis[p]) != p + 1u) store_out(out, f32, wg, 999.0f);  // sentinel
  }

  // ================= Phase 0: precompute GIX for ALL steps =================
  {
    const int slot0 = wg & 127;
    const int rg0 = slot0 >> 1, bg0 = slot0 & 1;
    stage_w(sA, W_ih, HID_ + EMB_, rg0, f32, tid);
    __syncthreads();
    const long bstride = (long)S_ * HID_;
    const long boffb = (long)(bg0 * 64) * S_ * HID_;
    for (int t = 0; t < 256; ++t) {
      const int it = ((wg >> 7) << 8) | t;
      f32x4 acc[3][4];
      #pragma unroll
      for (int rt = 0; rt < 3; ++rt)
        #pragma unroll
        for (int bt = 0; bt < 4; ++bt) acc[rt][bt] = f32x4{0.f, 0.f, 0.f, 0.f};
      const long boff = boffb + (long)it * HID_;
      if (f32) {
        const float* Bf = (const float*)hs + boff;
        #pragma unroll
        for (int kb = 0; kb < 8; ++kb) {
          const int k = kw0 + kb * 32;
          short8 avh[3];
          #pragma unroll
          for (int rt = 0; rt < 3; ++rt)
            avh[rt] = ld_bf8(&sA[(rt * 16 + m) * LDS_A_STRIDE + k]);
          short8 bxh[4], bxl[4];
          #pragma unroll
          for (int bt = 0; bt < 4; ++bt) {
            const float* bp = Bf + (long)(bt * 16 + m) * bstride + k;
            f32x4 x0 = *(const f32x4*)bp;
            f32x4 x1 = *(const f32x4*)(bp + 4);
            u16x8 th, tl;
            #pragma unroll
            for (int j = 0; j < 4; ++j) {
              unsigned short u0 = f2bf(x0[j]);
              th[j] = u0; tl[j] = f2bf(x0[j] - bf2f(u0));
              unsigned short u1 = f2bf(x1[j]);
              th[4 + j] = u1; tl[4 + j] = f2bf(x1[j] - bf2f(u1));
            }
            bxh[bt] = __builtin_bit_cast(short8, th);
            bxl[bt] = __builtin_bit_cast(short8, tl);
          }
          short8 avl[3];
          #pragma unroll
          for (int rt = 0; rt < 3; ++rt)
            avl[rt] = ld_bf8(&g_Wlox[(long)(rt * HID_ + rg0 * 16 + m) * HID_ + k]);
          #pragma unroll
          for (int rt = 0; rt < 3; ++rt)
            #pragma unroll
            for (int bt = 0; bt < 4; ++bt) {
              acc[rt][bt] = __builtin_amdgcn_mfma_f32_16x16x32_bf16(
                  avh[rt], bxh[bt], acc[rt][bt], 0, 0, 0);
              acc[rt][bt] = __builtin_amdgcn_mfma_f32_16x16x32_bf16(
                  avh[rt], bxl[bt], acc[rt][bt], 0, 0, 0);
              acc[rt][bt] = __builtin_amdgcn_mfma_f32_16x16x32_bf16(
                  avl[rt], bxh[bt], acc[rt][bt], 0, 0, 0);
              acc[rt][bt] = __builtin_amdgcn_mfma_f32_16x16x32_bf16(
                  avl[rt], bxl[bt], acc[rt][bt], 0, 0, 0);
            }
        }
      } else {
        const unsigned short* Bh = (const unsigned short*)hs + boff;
        #pragma unroll
        for (int kb = 0; kb < 8; ++kb) {
          const int k = kw0 + kb * 32;
          short8 avh[3], bxh[4];
          #pragma unroll
          for (int rt = 0; rt < 3; ++rt)
            avh[rt] = ld_bf8(&sA[(rt * 16 + m) * LDS_A_STRIDE + k]);
          #pragma unroll
          for (int bt = 0; bt < 4; ++bt)
            bxh[bt] = ld_bf8(&Bh[(long)(bt * 16 + m) * bstride + k]);
          #pragma unroll
          for (int rt = 0; rt < 3; ++rt)
            #pragma unroll
            for (int bt = 0; bt < 4; ++bt)
              acc[rt][bt] = __builtin_amdgcn_mfma_f32_16x16x32_bf16(
                  avh[rt], bxh[bt], acc[rt][bt], 0, 0, 0);
        }
      }
      __syncthreads();
      #pragma unroll
      for (int rt = 0; rt < 3; ++rt)
        #pragma unroll
        for (int bt = 0; bt < 4; ++bt)
          *(f32x4*)&sCp[(wv * 64 + bt * 16 + m) * CP_STRIDE + rt * 16 + q * 4] =
              acc[rt][bt];
      __syncthreads();
      #pragma unroll
      for (int g = 0; g < 3; ++g) {
        f32x4 sv = f32x4{0.f, 0.f, 0.f, 0.f};
        #pragma unroll
        for (int w = 0; w < 4; ++w)
          sv += *(const f32x4*)&sCp[(w * 64 + bl) * CP_STRIDE + g * 16 + jj];
        *(f32x4*)&g_GIXall[(((long)it * 128 + slot0) * 64 + bl) * 48 +
                           g * 16 + jj] = sv;
      }
      __syncthreads();
    }
  }
  __threadfence();   // one-time L2 writeback+inv: publish g_GIXall
  gridbar(wg, bar); ++bar;

  // ---- re-stage loop weights + W_out slice (h-WGs) + one-time preloads ----
  if (!isx) {
    stage_w(sA, W_hh, HID_, rg, f32, tid);
    for (int i = tid; i < NL_ * 16; i += 256) {   // sWo[l*16+tt] f32
      int l = i >> 4, tt = i & 15;
      sWo[i] = ldin(W_out, (long)l * HID_ + rg * 16 + tt, f32);
    }
  }
  __syncthreads();

  float bo = 0.f;
  if (isx && tid < 32) bo = ldin(b_out, tid, f32);
  f32x4 bhh[3];
  if (!isx) {
    const int jbase = rg * 16 + jj;
    #pragma unroll
    for (int g = 0; g < 3; ++g)
      #pragma unroll
      for (int t = 0; t < 4; ++t)
        bhh[g][t] = ldin(b_hh, (long)g * HID_ + jbase + t, f32);
  }

  float hreg[4] = {0.f, 0.f, 0.f, 0.f};  // fp32 h master (h-WGs)
  f32x4 sred[3];

  // ============== sequential loop: 1 visibility hop on critical path ======
  for (int it = 0; it <= S_; ++it) {
    if (isx && it >= 1) {
      // ---- x-WG: sum logits partials of step it-1, argmax, publish pred --
      wait_hseq(wg >> 6, it);   // stamps it => h_{it-1} + partials(it-1)
      // ---- h-liveness self-test (once) ----
      if (it == 1 && wg == 0 && tid == 0) {
        u64_t a = ald64(&g_hhi[0][0]) | ald64(&g_hhi[0][4]) |
                  ald64(&g_hhi[0][8]) | ald64(&g_hhi[0][12]);
        if (a == 0ull) store_out(out, f32, 300, 555.0f);      // sentinel
      }
      const int b = wg, s = it - 1;
      {  // 8 threads per label: c-th thread sums rg = c*8..c*8+7 in order
        int l = tid & 31, c = tid >> 5;
        float p = 0.f;
        #pragma unroll
        for (int j = 0; j < 8; ++j)
          p += aldf(&g_lp[(((c * 8 + j) * 128) + b) * 32 + l]);
        sCp[l * 8 + c] = p;
      }
      __syncthreads();
      if (tid < 32) {
        const float* pp = sCp + tid * 8;
        // strict rg-order combine (c ascending), + bo last
        float v = pp[0];
        v += pp[1]; v += pp[2]; v += pp[3];
        v += pp[4]; v += pp[5]; v += pp[6]; v += pp[7];
        v += bo;
        store_out(out, f32, ((long)b * S_ + s) * NL_ + tid, v);
        float bv = v; int bi = tid;
        #pragma unroll
        for (int off = 16; off; off >>= 1) {
          float v2 = __shfl_down(bv, off, 32);
          int   i2 = __shfl_down(bi, off, 32);
          if (v2 > bv || (v2 == bv && i2 < bi)) { bv = v2; bi = i2; }
        }
        // packed pred word: (it<<8)|pred. Value inside word -> no fence.
        if (tid == 0) ast32(&g_predw[b * 16], ((unsigned)it << 8) | (unsigned)bi);
      }
      __syncthreads();
    }

    if (!isx && it < S_) {
      // ---- prefetch this step's GIX tile (plain cached, h-independent) ----
      f32x4 gixp[3];
      #pragma unroll
      for (int g = 0; g < 3; ++g)
        gixp[g] = *(const f32x4*)&g_GIXall[(((long)it * 128 + slot) * 64 + bl)
                                           * 48 + g * 16 + jj];

      wait_hseq(bg, it);             // h_{it-1} of my half published
      const int rb = (it + 1) & 1;   // read parity (h_{it-1})
      const int wb = it & 1;         // write parity (h_it)

      // ---- 48x64 tile GEMM gh = W_hh @ h, K=1024 (h via LLC atomics) ----
      f32x4 acc[3][4];
      #pragma unroll
      for (int rt = 0; rt < 3; ++rt)
        #pragma unroll
        for (int bt = 0; bt < 4; ++bt) acc[rt][bt] = f32x4{0.f, 0.f, 0.f, 0.f};

      const unsigned short* Bhi = g_hhi[rb] + (long)(bg * 64) * HID_;
      const unsigned short* Blo = g_hlo[rb] + (long)(bg * 64) * HID_;
      #pragma unroll
      for (int kb = 0; kb < 8; ++kb) {
        const int k = kw0 + kb * 32;
        short8 avh[3], bh[4], blv[4];
        #pragma unroll
        for (int rt = 0; rt < 3; ++rt)
          avh[rt] = ld_bf8(&sA[(rt * 16 + m) * LDS_A_STRIDE + k]);
        #pragma unroll
        for (int bt = 0; bt < 4; ++bt) {
          bh[bt]  = ld_bf8_coh(&Bhi[(long)(bt * 16 + m) * HID_ + k]);
          blv[bt] = ld_bf8_coh(&Blo[(long)(bt * 16 + m) * HID_ + k]);
        }
        #pragma unroll
        for (int rt = 0; rt < 3; ++rt)
          #pragma unroll
          for (int bt = 0; bt < 4; ++bt) {
            acc[rt][bt] = __builtin_amdgcn_mfma_f32_16x16x32_bf16(
                avh[rt], bh[bt], acc[rt][bt], 0, 0, 0);
            acc[rt][bt] = __builtin_amdgcn_mfma_f32_16x16x32_bf16(
                avh[rt], blv[bt], acc[rt][bt], 0, 0, 0);
          }
        if (f32) {
          short8 avl[3];
          #pragma unroll
          for (int rt = 0; rt < 3; ++rt)
            avl[rt] = ld_bf8(&g_Wlohh[(long)(rt * HID_ + rg * 16 + m) * HID_ + k]);
          #pragma unroll
          for (int rt = 0; rt < 3; ++rt)
            #pragma unroll
            for (int bt = 0; bt < 4; ++bt) {
              acc[rt][bt] = __builtin_amdgcn_mfma_f32_16x16x32_bf16(
                  avl[rt], bh[bt], acc[rt][bt], 0, 0, 0);
              acc[rt][bt] = __builtin_amdgcn_mfma_f32_16x16x32_bf16(
                  avl[rt], blv[bt], acc[rt][bt], 0, 0, 0);
            }
        }
      }

      __syncthreads();  // protect sCp (prior partial scratch fully read)
      #pragma unroll
      for (int rt = 0; rt < 3; ++rt)
        #pragma unroll
        for (int bt = 0; bt < 4; ++bt)
          *(f32x4*)&sCp[(wv * 64 + bt * 16 + m) * CP_STRIDE + rt * 16 + q * 4] =
              acc[rt][bt];
      __syncthreads();
      #pragma unroll
      for (int g = 0; g < 3; ++g) {
        f32x4 sv = f32x4{0.f, 0.f, 0.f, 0.f};
        #pragma unroll
        for (int w = 0; w < 4; ++w)
          sv += *(const f32x4*)&sCp[(w * 64 + bl) * CP_STRIDE + g * 16 + jj];
        sred[g] = sv;
      }
      __syncthreads();  // all sCp reads done before partial scratch reuse

      // ---- per-row pred wait: own padded word, read-only spin, no RMW ----
      const int bglob = bg * 64 + bl;
      int pb = 0;
      if (it >= 1) {
        const unsigned int* pw = &g_predw[bglob * 16];
        unsigned w = ald32(pw);
        while ((int)(w >> 8) < it) { w = ald32(pw); }
        pb = (int)(w & 255u);
      }
      __builtin_amdgcn_sched_barrier(0);

      // ---- gate epilogue: h_new for (bglob, jbase..jbase+3) ----
      const int jbase = rg * 16 + jj;
      const float* gl = g_Glab + (long)pb * G3_;
      f32x4 glab[3];
      #pragma unroll
      for (int g = 0; g < 3; ++g)
        glab[g] = *(const f32x4*)&gl[g * HID_ + jbase];
      u16x4 whi, wlo;
      #pragma unroll
      for (int t4 = 0; t4 < 4; ++t4) {
        float ghr = sred[0][t4] + bhh[0][t4];
        float ghz = sred[1][t4] + bhh[1][t4];
        float ghn = sred[2][t4] + bhh[2][t4];
        float gir = gixp[0][t4] + glab[0][t4];   // b_ih folded into G_lab
        float giz = gixp[1][t4] + glab[1][t4];
        float gin = gixp[2][t4] + glab[2][t4];
        float r = 1.f / (1.f + expf(-(gir + ghr)));
        float z = 1.f / (1.f + expf(-(giz + ghz)));
        float n = tanhf(gin + r * ghn);   // b_hh_n inside r*(...) per PyTorch
        float hn = (1.f - z) * n + z * hreg[t4];
        hreg[t4] = hn;
        unsigned short uhi = f2bf(hn);
        whi[t4] = uhi;
        wlo[t4] = f2bf(hn - bf2f(uhi));
      }
      st_h4_coh(&g_hhi[wb][(long)bglob * HID_ + jbase], whi);
      st_h4_coh(&g_hlo[wb][(long)bglob * HID_ + jbase], wlo);

      // ---- logits partials from exact fp32 h_new (strict col order) ----
      // scratch: sCp[tid*32 + l] = dot of this thread's 4 cols (t-order)
      #pragma unroll
      for (int l0 = 0; l0 < 32; l0 += 4) {
        f32x4 pv;
        #pragma unroll
        for (int dl = 0; dl < 4; ++dl) {
          const float* wv4 = &sWo[(l0 + dl) * 16 + jj];
          float pl = wv4[0] * hreg[0];
          pl += wv4[1] * hreg[1];
          pl += wv4[2] * hreg[2];
          pl += wv4[3] * hreg[3];
          pv[dl] = pl;
        }
        *(f32x4*)&sCp[tid * 32 + l0] = pv;
      }
      __syncthreads();
      {  // reduce 4 jj-groups in w-order; thread: row b2 = tid>>2, 8 labels
        const int b2 = tid >> 2, l0 = (tid & 3) * 8;
        f32x4 s0 = *(const f32x4*)&sCp[(0 * 64 + b2) * 32 + l0];
        f32x4 s1 = *(const f32x4*)&sCp[(0 * 64 + b2) * 32 + l0 + 4];
        #pragma unroll
        for (int w = 1; w < 4; ++w) {
          s0 += *(const f32x4*)&sCp[(w * 64 + b2) * 32 + l0];
          s1 += *(const f32x4*)&sCp[(w * 64 + b2) * 32 + l0 + 4];
        }
        float* lp = &g_lp[((long)rg * 128 + bg * 64 + b2) * 32 + l0];
        st_f2_coh(lp + 0, s0[0], s0[1]);
        st_f2_coh(lp + 2, s0[2], s0[3]);
        st_f2_coh(lp + 4, s1[0], s1[1]);
        st_f2_coh(lp + 6, s1[2], s1[3]);
      }

      // ---- publish: h limbs + partials drained to LLC, then stamp ----
      asm volatile("s_waitcnt vmcnt(0)" ::: "memory");
      __syncthreads();
      if (tid == 0) ast32(&g_hseq[bg][rg * 16], (unsigned)(it + 1));
    }
  }
}

extern "C" void kernel_launch(void* const* d_in, const int* in_sizes, int n_in,
                              void* d_out, int out_size, void* d_ws, size_t ws_size,
                              hipStream_t stream) {
  const void* hs    = d_in[0];
  const void* emb   = d_in[1];
  const void* W_ih  = d_in[2];
  const void* W_hh  = d_in[3];
  const void* b_ih  = d_in[4];
  const void* b_hh  = d_in[5];
  const void* W_out = d_in[6];
  const void* b_out = d_in[7];

  hipLaunchKernelGGL(k_zero, dim3(256), dim3(256), 0, stream);
  hipLaunchKernelGGL(k_detect, dim3(1), dim3(64), 0, stream,
                     (const unsigned short*)W_ih);
  hipLaunchKernelGGL(k_prep, dim3(32 * 12), dim3(256), 0, stream,
                     emb, W_ih, b_ih);
  hipLaunchKernelGGL(k_prepw, dim3(3072), dim3(256), 0, stream, W_ih, W_hh);
  hipFuncSetAttribute((const void*)k_seq,
                      hipFuncAttributeMaxDynamicSharedMemorySize, LDS_BYTES);
  hipLaunchKernelGGL(k_seq, dim3(256), dim3(256), LDS_BYTES, stream,
                     hs, W_ih, W_hh, b_hh, W_out, b_out, d_out);
}

// Round 6
// 15196.037 us; speedup vs baseline: 1.1174x; 1.1174x over previous
//
#include <hip/hip_runtime.h>

// Autoregressive GRU decoder. B=128, S=512, HID=1024, EMB=128, NL=32.
//
// Input dtype (fp32 vs bf16) detected on-device; OUTPUT FORMAT IS COUPLED
// to the detected input dtype (f32 -> float out, bf16 -> u16 bf16 out).
//
// Numerics (fp32 mode): W = Whi(bf16,LDS) + Wlo(bf16, device-global,
// precomputed); x and h split hi/lo bf16 in-register. All 4 limb products
// go through bf16 MFMA into one fp32 accumulator. G_lab in fp64. Logits
// from exact fp32 h.
//
// STRUCTURE (this revision): TWO kernels so rocprof attributes time.
//  k_gix: phase 0 -- GIX[s] = W_ihX @ x_s for ALL 512 steps into g_GIXall
//    (805 MB), plain stores. Kernel boundary publishes (implicit HSA
//    release) -- no fences needed.
//  k_loop: sequential recurrence, R3-best config:
//    - bulk payloads PLAIN cached loads/stores; ONE release fence
//      (buffer_wbl2) per producer step, ONE acquire fence (buffer_inv)
//      per consumer step. Atomics (sc0|sc1) only for stamp words.
//    - h publication: plain stores -> vmcnt(0) -> barrier -> tid0
//      fence(release) + stamp g_hseq[bg][rg*16]=it+1. Consumers poll 64
//      stamp lines (wave 0, one per lane, s_sleep(1) backoff), tid0
//      fence(acquire), barrier, then plain b128 GEMM loads.
//    - pred: x-WG b packs (it<<8)|pred into its own padded word; h
//      epilogue threads spin on their row's word (s_sleep backoff).
//      Value is inside the word -> no fence. Spin + G_lab load issue
//      hoisted before the LDS reduction to overlap.
//    - Double-buffered h by step parity closes WAR (per-row pred gating
//      closes the x-read vs h-overwrite WAR).
//  Spin backoff s_sleep(1) everywhere: cuts LLC poll pressure.
//  Sentinels 999/555 self-test visibility.

#define S_    512
#define HID_  1024
#define EMB_  128
#define NL_   32
#define G3_   3072

#define LDS_A_STRIDE 1032                      // 1024 + 8 pad (bf16 elems)
#define LDS_A_BYTES  (48 * LDS_A_STRIDE * 2)   // 99072
#define CP_STRIDE    52                        // fp32 elems, pad 48->52
#define LDS_CP_BYTES (4 * 64 * CP_STRIDE * 4)  // 53248
#define LDS_BYTES    (LDS_A_BYTES + LDS_CP_BYTES) // 152320 <= 160KiB

typedef __attribute__((ext_vector_type(8))) short          short8;
typedef __attribute__((ext_vector_type(8))) unsigned short u16x8;
typedef __attribute__((ext_vector_type(4))) unsigned short u16x4;
typedef __attribute__((ext_vector_type(4))) float          f32x4;
typedef unsigned long long u64_t;

// ---------------- device-global state (no d_ws dependence) ---------------
__device__ unsigned int   g_ctr[576];           // 8 groups @ +g*64, root @ +512
__device__ unsigned int   g_flag[1];
__device__ unsigned int   g_vis[256];
__device__ unsigned int   g_hseq[2][64 * 16];   // [half][rg*16], line-padded
__device__ unsigned int   g_predw[128 * 16];    // [b*16]: (it<<8)|pred
__device__ unsigned short g_hhi[2][128 * HID_]; // double-buffered by parity
__device__ unsigned short g_hlo[2][128 * HID_];
__device__ float          g_hf32[2][128 * HID_];
__device__ float          g_Glab[NL_ * G3_];    // b_ih folded in
__device__ unsigned short g_Wlox[G3_ * HID_];   // lo limb of W_ih x-part
__device__ unsigned short g_Wlohh[G3_ * HID_];  // lo limb of W_hh
// GIX for all steps: [it][slot][bl][48] -- 512*128*64*48 fp32 = 805 MB BSS.
__device__ float          g_GIXall[(size_t)S_ * 128 * 64 * 48];

__device__ __forceinline__ float bf2f(unsigned short u) {
  union { unsigned int i; float f; } v; v.i = ((unsigned int)u) << 16; return v.f;
}
__device__ __forceinline__ unsigned short f2bf(float f) {
  union { float f; unsigned int i; } v; v.f = f;
  unsigned int u = v.i;
  return (unsigned short)((u + 0x7FFFu + ((u >> 16) & 1u)) >> 16);
}
__device__ __forceinline__ short8 ld_bf8(const unsigned short* p) {
  return __builtin_bit_cast(short8, *(const u16x8*)p);
}
__device__ __forceinline__ float ldin(const void* p, long i, int f32) {
  return f32 ? ((const float*)p)[i] : bf2f(((const unsigned short*)p)[i]);
}
__device__ __forceinline__ void store_out(void* out, int f32, long idx, float v) {
  if (f32) ((float*)out)[idx] = v;
  else     ((unsigned short*)out)[idx] = f2bf(v);
}

// ---- atomic (LLC) helpers: ONLY stamp words / sentinels ----
__device__ __forceinline__ unsigned int ald32(const unsigned int* p) {
  return __hip_atomic_load(p, __ATOMIC_RELAXED, __HIP_MEMORY_SCOPE_AGENT);
}
__device__ __forceinline__ void ast32(unsigned int* p, unsigned int v) {
  __hip_atomic_store(p, v, __ATOMIC_RELAXED, __HIP_MEMORY_SCOPE_AGENT);
}

// ---- zero state each launch ----
__global__ void k_zero() {
  int t = blockIdx.x * 256 + threadIdx.x;       // 65536 threads
  if (t < 576) g_ctr[t] = 0u;
  else if (t < 832) g_vis[t - 576] = 0u;
  if (t >= 2048 && t < 4096) ((unsigned int*)g_hseq)[t - 2048] = 0u;
  if (t >= 4096 && t < 6144) g_predw[t - 4096] = 0u;
  const u16x4 z4 = {0, 0, 0, 0};
  const f32x4 zf = {0.f, 0.f, 0.f, 0.f};
  for (int i = t; i < 2 * 128 * HID_ / 4; i += 65536) {
    ((u16x4*)g_hhi)[i] = z4;
    ((u16x4*)g_hlo)[i] = z4;
    ((f32x4*)g_hf32)[i] = zf;
  }
}

// ---- dtype detector: bf16 W_ih bounded by 1/32; fp32 misread blows up ----
__global__ void k_detect(const unsigned short* __restrict__ W) {
  unsigned bad = 0;
  for (int i = threadIdx.x; i < 1024; i += 64) {
    float v = bf2f(W[i]);
    if (!(v * v <= 1.0f)) bad = 1;   // catches |v|>1 and NaN
  }
  unsigned long long b = __ballot(bad != 0);
  if (threadIdx.x == 0) g_flag[0] = (b != 0ull) ? 1u : 0u;
}

// ---- prep: G_lab[l][n] = b_ih[n] + sum_e emb[l][e]*W_ih[n][1024+e] (fp64) --
__global__ void k_prep(const void* __restrict__ emb,
                       const void* __restrict__ W_ih,
                       const void* __restrict__ b_ih) {
  const int f32 = (int)g_flag[0];
  int l = blockIdx.x / 12;
  int n = (blockIdx.x % 12) * 256 + threadIdx.x;
  double acc = (double)ldin(b_ih, n, f32);
  for (int e = 0; e < EMB_; ++e)
    acc += (double)ldin(emb, (long)l * EMB_ + e, f32) *
           (double)ldin(W_ih, (long)n * (HID_ + EMB_) + HID_ + e, f32);
  g_Glab[l * G3_ + n] = (float)acc;
}

// ---- prep: lo limbs of W (fp32 mode only) ----
__global__ void k_prepw(const void* __restrict__ W_ih,
                        const void* __restrict__ W_hh) {
  if (!g_flag[0]) return;
  long i4 = ((long)blockIdx.x * 256 + threadIdx.x) * 4;  // 3072 blocks
  if (i4 >= (long)G3_ * HID_) return;
  int row = (int)(i4 >> 10), col = (int)(i4 & 1023);
  f32x4 wh = *(const f32x4*)&((const float*)W_hh)[(long)row * HID_ + col];
  f32x4 wx = *(const f32x4*)&((const float*)W_ih)[(long)row * (HID_ + EMB_) + col];
  u16x4 lh, lx;
  #pragma unroll
  for (int j = 0; j < 4; ++j) {
    unsigned short h1 = f2bf(wh[j]);
    lh[j] = f2bf(wh[j] - bf2f(h1));
    unsigned short x1 = f2bf(wx[j]);
    lx[j] = f2bf(wx[j] - bf2f(x1));
  }
  *(u16x4*)&g_Wlohh[i4] = lh;
  *(u16x4*)&g_Wlox[i4]  = lx;
}

// ---- 2-level device barrier (startup probe only) ----
__device__ __forceinline__ void gridbar(int wg, int bar) {
  __syncthreads();
  if (threadIdx.x == 0) {
    asm volatile("s_waitcnt vmcnt(0)" ::: "memory");
    unsigned int* c1   = g_ctr + (wg & 7) * 64;
    unsigned int* root = g_ctr + 512;
    unsigned int old = __hip_atomic_fetch_add(c1, 1u, __ATOMIC_RELAXED,
                                              __HIP_MEMORY_SCOPE_AGENT);
    if (old == 32u * (unsigned)(bar + 1) - 1u)
      __hip_atomic_fetch_add(root, 1u, __ATOMIC_RELAXED,
                             __HIP_MEMORY_SCOPE_AGENT);
    unsigned int tgt = 8u * (unsigned)(bar + 1);
    while (__hip_atomic_load(root, __ATOMIC_RELAXED,
                             __HIP_MEMORY_SCOPE_AGENT) < tgt)
      __builtin_amdgcn_s_sleep(2);
  }
  __syncthreads();
}

// ---- wait until all 64 producers of `half` stamped >= it, then ACQUIRE ----
__device__ __forceinline__ void wait_hseq_acq(int half, int it) {
  if (threadIdx.x < 64) {
    const unsigned int* p = &g_hseq[half][threadIdx.x * 16];
    while ((int)ald32(p) < it) __builtin_amdgcn_s_sleep(1);
  }
  __builtin_amdgcn_sched_barrier(0);
  __syncthreads();
  if (threadIdx.x == 0)
    __builtin_amdgcn_fence(__ATOMIC_ACQUIRE, "agent");   // buffer_inv
  __syncthreads();   // all waves' loads start after the inv completed
}

// ---- stage 48-row hi-limb weight slice (rows [r16][z16][n16] of group rg) --
__device__ __forceinline__ void stage_w(unsigned short* sA, const void* Wsrc,
                                        int wstride, int rg, int f32, int tid) {
  if (f32) {
    const float* Ws = (const float*)Wsrc;
    for (int i = tid; i < 48 * 1024 / 4; i += 256) {
      int e = i * 4, row = e >> 10, k4 = e & 1023;
      int grow = (row >> 4) * HID_ + rg * 16 + (row & 15);
      f32x4 v = *(const f32x4*)&Ws[(long)grow * wstride + k4];
      u16x4 o;
      #pragma unroll
      for (int j = 0; j < 4; ++j) o[j] = f2bf(v[j]);
      *(u16x4*)&sA[row * LDS_A_STRIDE + k4] = o;
    }
  } else {
    const unsigned short* Ws = (const unsigned short*)Wsrc;
    for (int i = tid; i < 48 * 1024 / 4; i += 256) {
      int e = i * 4, row = e >> 10, k4 = e & 1023;
      int grow = (row >> 4) * HID_ + rg * 16 + (row & 15);
      *(u16x4*)&sA[row * LDS_A_STRIDE + k4] =
          *(const u16x4*)&Ws[(long)grow * wstride + k4];
    }
  }
}

// ================= k_gix: GIX[s] for ALL steps (barrier-free) ============
// WG wg handles slot0 = wg&127 for 256 steps (wg<128: steps 0..255,
// wg>=128: 256..511). Plain stores; kernel end publishes device-wide.
__global__ __launch_bounds__(256) void k_gix(const void* __restrict__ hs,
                                             const void* __restrict__ W_ih) {
  extern __shared__ char smem[];
  unsigned short* sA  = (unsigned short*)smem;
  float*          sCp = (float*)(smem + LDS_A_BYTES);

  const int f32 = (int)g_flag[0];
  const int tid = threadIdx.x;
  const int wg  = blockIdx.x;
  const int lane = tid & 63, wv = tid >> 6;
  const int m = lane & 15, q = lane >> 4;
  const int bl = tid & 63;
  const int jj = (tid >> 6) * 4;
  const int kw0 = wv * 256 + q * 8;

  const int slot0 = wg & 127;
  const int rg0 = slot0 >> 1, bg0 = slot0 & 1;
  stage_w(sA, W_ih, HID_ + EMB_, rg0, f32, tid);
  __syncthreads();
  const long bstride = (long)S_ * HID_;
  const long boffb = (long)(bg0 * 64) * S_ * HID_;
  for (int t = 0; t < 256; ++t) {
    const int it = ((wg >> 7) << 8) | t;
    f32x4 acc[3][4];
    #pragma unroll
    for (int rt = 0; rt < 3; ++rt)
      #pragma unroll
      for (int bt = 0; bt < 4; ++bt) acc[rt][bt] = f32x4{0.f, 0.f, 0.f, 0.f};
    const long boff = boffb + (long)it * HID_;
    if (f32) {
      const float* Bf = (const float*)hs + boff;
      #pragma unroll
      for (int kb = 0; kb < 8; ++kb) {
        const int k = kw0 + kb * 32;
        short8 avh[3];
        #pragma unroll
        for (int rt = 0; rt < 3; ++rt)
          avh[rt] = ld_bf8(&sA[(rt * 16 + m) * LDS_A_STRIDE + k]);
        short8 bxh[4], bxl[4];
        #pragma unroll
        for (int bt = 0; bt < 4; ++bt) {
          const float* bp = Bf + (long)(bt * 16 + m) * bstride + k;
          f32x4 x0 = *(const f32x4*)bp;
          f32x4 x1 = *(const f32x4*)(bp + 4);
          u16x8 th, tl;
          #pragma unroll
          for (int j = 0; j < 4; ++j) {
            unsigned short u0 = f2bf(x0[j]);
            th[j] = u0; tl[j] = f2bf(x0[j] - bf2f(u0));
            unsigned short u1 = f2bf(x1[j]);
            th[4 + j] = u1; tl[4 + j] = f2bf(x1[j] - bf2f(u1));
          }
          bxh[bt] = __builtin_bit_cast(short8, th);
          bxl[bt] = __builtin_bit_cast(short8, tl);
        }
        short8 avl[3];
        #pragma unroll
        for (int rt = 0; rt < 3; ++rt)
          avl[rt] = ld_bf8(&g_Wlox[(long)(rt * HID_ + rg0 * 16 + m) * HID_ + k]);
        #pragma unroll
        for (int rt = 0; rt < 3; ++rt)
          #pragma unroll
          for (int bt = 0; bt < 4; ++bt) {
            acc[rt][bt] = __builtin_amdgcn_mfma_f32_16x16x32_bf16(
                avh[rt], bxh[bt], acc[rt][bt], 0, 0, 0);
            acc[rt][bt] = __builtin_amdgcn_mfma_f32_16x16x32_bf16(
                avh[rt], bxl[bt], acc[rt][bt], 0, 0, 0);
            acc[rt][bt] = __builtin_amdgcn_mfma_f32_16x16x32_bf16(
                avl[rt], bxh[bt], acc[rt][bt], 0, 0, 0);
            acc[rt][bt] = __builtin_amdgcn_mfma_f32_16x16x32_bf16(
                avl[rt], bxl[bt], acc[rt][bt], 0, 0, 0);
          }
      }
    } else {
      const unsigned short* Bh = (const unsigned short*)hs + boff;
      #pragma unroll
      for (int kb = 0; kb < 8; ++kb) {
        const int k = kw0 + kb * 32;
        short8 avh[3], bxh[4];
        #pragma unroll
        for (int rt = 0; rt < 3; ++rt)
          avh[rt] = ld_bf8(&sA[(rt * 16 + m) * LDS_A_STRIDE + k]);
        #pragma unroll
        for (int bt = 0; bt < 4; ++bt)
          bxh[bt] = ld_bf8(&Bh[(long)(bt * 16 + m) * bstride + k]);
        #pragma unroll
        for (int rt = 0; rt < 3; ++rt)
          #pragma unroll
          for (int bt = 0; bt < 4; ++bt)
            acc[rt][bt] = __builtin_amdgcn_mfma_f32_16x16x32_bf16(
                avh[rt], bxh[bt], acc[rt][bt], 0, 0, 0);
      }
    }
    __syncthreads();
    #pragma unroll
    for (int rt = 0; rt < 3; ++rt)
      #pragma unroll
      for (int bt = 0; bt < 4; ++bt)
        *(f32x4*)&sCp[(wv * 64 + bt * 16 + m) * CP_STRIDE + rt * 16 + q * 4] =
            acc[rt][bt];
    __syncthreads();
    #pragma unroll
    for (int g = 0; g < 3; ++g) {
      f32x4 sv = f32x4{0.f, 0.f, 0.f, 0.f};
      #pragma unroll
      for (int w = 0; w < 4; ++w)
        sv += *(const f32x4*)&sCp[(w * 64 + bl) * CP_STRIDE + g * 16 + jj];
      *(f32x4*)&g_GIXall[(((long)it * 128 + slot0) * 64 + bl) * 48 +
                         g * 16 + jj] = sv;
    }
    __syncthreads();
  }
}

// ================= k_loop: sequential recurrence =========================
__global__ __launch_bounds__(256) void k_loop(
    const void* __restrict__ W_hh,
    const void* __restrict__ b_hh,
    const void* __restrict__ W_out,
    const void* __restrict__ b_out,
    void* __restrict__ out) {
  extern __shared__ char smem[];
  unsigned short* sA  = (unsigned short*)smem;
  float*          sCp = (float*)(smem + LDS_A_BYTES);

  const int f32 = (int)g_flag[0];
  const int tid = threadIdx.x;
  const int wg  = blockIdx.x;
  const bool isx = (wg < 128);
  const int lid  = isx ? wg : wg - 128;
  const int rg = lid >> 1, bg = lid & 1;
  const int slot = lid;                 // (rg,bg) slot
  const int lane = tid & 63, wv = tid >> 6;
  const int m = lane & 15, q = lane >> 4;
  const int bl = tid & 63;              // epilogue local batch
  const int jj = (tid >> 6) * 4;        // epilogue local j base
  const int kw0 = wv * 256 + q * 8;

  // ---- visibility self-test (probe barrier, bar 0) ----
  if (tid == 0) ast32(&g_vis[wg], (unsigned)wg + 1u);
  gridbar(wg, 0);
  if (tid == 0) {
    unsigned p = ((unsigned)wg + 37u) & 255u;
    if (ald32(&g_vis[p]) != p + 1u) store_out(out, f32, wg, 999.0f);  // sentinel
  }

  // ---- stage loop weights (h-WGs only) + one-time preloads ----
  if (!isx) stage_w(sA, W_hh, HID_, rg, f32, tid);
  __syncthreads();

  float bo = 0.f;
  if (isx && tid < 32) bo = ldin(b_out, tid, f32);
  f32x4 bhh[3];
  if (!isx) {
    const int jbase = rg * 16 + jj;
    #pragma unroll
    for (int g = 0; g < 3; ++g)
      #pragma unroll
      for (int t = 0; t < 4; ++t)
        bhh[g][t] = ldin(b_hh, (long)g * HID_ + jbase + t, f32);
  }

  float hreg[4] = {0.f, 0.f, 0.f, 0.f};  // fp32 h master (h-WGs)
  f32x4 sred[3];

  for (int it = 0; it <= S_; ++it) {
    if (isx && it >= 1) {
      wait_hseq_acq(wg >> 6, it);    // h_{it-1} of my half published + inv
      const int rb = (it + 1) & 1;   // parity of it-1
      // ---- h-liveness self-test (once) ----
      if (it == 1 && wg == 0 && tid == 0) {
        float s = 0.f;
        for (int i = 0; i < 32; ++i) s += g_hf32[0][i] * g_hf32[0][i];
        if (s == 0.f) store_out(out, f32, 300, 555.0f);       // sentinel
      }
      // ---- logits + argmax for step it-1, batch b = wg (fp32 h) ----
      const int b = wg, s = it - 1;
      float* scrp  = sCp;          // 256 fp32 partials
      float* shrow = sCp + 256;    // 8 blocks x 132 (pad) staged h row
      {
        f32x4 hv = *(const f32x4*)&g_hf32[rb][(long)b * HID_ + tid * 4];
        *(f32x4*)&shrow[(tid >> 5) * 132 + (tid & 31) * 4] = hv;
      }
      __syncthreads();
      {
        int l = tid >> 3, kc = tid & 7;
        const float* hr = shrow + kc * 132;
        float p = 0.f;
        if (f32) {
          const float* wr = (const float*)W_out + (long)l * HID_ + kc * 128;
          for (int k = 0; k < 128; k += 4) {
            f32x4 wa = *(const f32x4*)&wr[k];
            f32x4 ha = *(const f32x4*)&hr[k];
            #pragma unroll
            for (int j = 0; j < 4; ++j) p += wa[j] * ha[j];
          }
        } else {
          const unsigned short* wr =
              (const unsigned short*)W_out + (long)l * HID_ + kc * 128;
          for (int k = 0; k < 128; k += 8) {
            u16x8 w8 = *(const u16x8*)&wr[k];
            f32x4 ha = *(const f32x4*)&hr[k];
            f32x4 hb = *(const f32x4*)&hr[k + 4];
            #pragma unroll
            for (int j = 0; j < 4; ++j) {
              p += bf2f(w8[j]) * ha[j];
              p += bf2f(w8[4 + j]) * hb[j];
            }
          }
        }
        scrp[tid] = p;
      }
      __syncthreads();
      if (tid < 32) {
        const float* pp = sCp + tid * 8;
        float v = pp[0] + pp[1] + pp[2] + pp[3] + pp[4] + pp[5] + pp[6] + pp[7]
                  + bo;
        store_out(out, f32, ((long)b * S_ + s) * NL_ + tid, v);
        float bv = v; int bi = tid;
        #pragma unroll
        for (int off = 16; off; off >>= 1) {
          float v2 = __shfl_down(bv, off, 32);
          int   i2 = __shfl_down(bi, off, 32);
          if (v2 > bv || (v2 == bv && i2 < bi)) { bv = v2; bi = i2; }
        }
        // packed pred word: (it<<8)|pred. Value inside word -> no fence.
        if (tid == 0) ast32(&g_predw[b * 16], ((unsigned)it << 8) | (unsigned)bi);
      }
      __syncthreads();
    }

    if (!isx && it < S_) {
      // ---- prefetch this step's GIX tile (plain cached, h-independent) ----
      f32x4 gixp[3];
      #pragma unroll
      for (int g = 0; g < 3; ++g)
        gixp[g] = *(const f32x4*)&g_GIXall[(((long)it * 128 + slot) * 64 + bl)
                                           * 48 + g * 16 + jj];

      wait_hseq_acq(bg, it);         // h_{it-1} of my half published + inv
      const int rb = (it + 1) & 1;   // read parity (h_{it-1})
      const int wb = it & 1;         // write parity (h_it)

      // ---- 48x64 tile GEMM gh = W_hh @ h, K=1024, PLAIN cached loads ----
      f32x4 acc[3][4];
      #pragma unroll
      for (int rt = 0; rt < 3; ++rt)
        #pragma unroll
        for (int bt = 0; bt < 4; ++bt) acc[rt][bt] = f32x4{0.f, 0.f, 0.f, 0.f};

      const unsigned short* Bhi = g_hhi[rb] + (long)(bg * 64) * HID_;
      const unsigned short* Blo = g_hlo[rb] + (long)(bg * 64) * HID_;
      #pragma unroll
      for (int kb = 0; kb < 8; ++kb) {
        const int k = kw0 + kb * 32;
        short8 avh[3], bh[4], blv[4];
        #pragma unroll
        for (int rt = 0; rt < 3; ++rt)
          avh[rt] = ld_bf8(&sA[(rt * 16 + m) * LDS_A_STRIDE + k]);
        #pragma unroll
        for (int bt = 0; bt < 4; ++bt) {
          bh[bt]  = ld_bf8(&Bhi[(long)(bt * 16 + m) * HID_ + k]);
          blv[bt] = ld_bf8(&Blo[(long)(bt * 16 + m) * HID_ + k]);
        }
        #pragma unroll
        for (int rt = 0; rt < 3; ++rt)
          #pragma unroll
          for (int bt = 0; bt < 4; ++bt) {
            acc[rt][bt] = __builtin_amdgcn_mfma_f32_16x16x32_bf16(
                avh[rt], bh[bt], acc[rt][bt], 0, 0, 0);
            acc[rt][bt] = __builtin_amdgcn_mfma_f32_16x16x32_bf16(
                avh[rt], blv[bt], acc[rt][bt], 0, 0, 0);
          }
        if (f32) {
          short8 avl[3];
          #pragma unroll
          for (int rt = 0; rt < 3; ++rt)
            avl[rt] = ld_bf8(&g_Wlohh[(long)(rt * HID_ + rg * 16 + m) * HID_ + k]);
          #pragma unroll
          for (int rt = 0; rt < 3; ++rt)
            #pragma unroll
            for (int bt = 0; bt < 4; ++bt) {
              acc[rt][bt] = __builtin_amdgcn_mfma_f32_16x16x32_bf16(
                  avl[rt], bh[bt], acc[rt][bt], 0, 0, 0);
              acc[rt][bt] = __builtin_amdgcn_mfma_f32_16x16x32_bf16(
                  avl[rt], blv[bt], acc[rt][bt], 0, 0, 0);
            }
        }
      }

      // ---- pred wait + G_lab issue EARLY (overlaps the LDS reduction) ----
      const int bglob = bg * 64 + bl;
      const int jbase = rg * 16 + jj;
      int pb = 0;
      if (it >= 1) {
        const unsigned int* pw = &g_predw[bglob * 16];
        unsigned w = ald32(pw);
        while ((int)(w >> 8) < it) {
          __builtin_amdgcn_s_sleep(1);
          w = ald32(pw);
        }
        pb = (int)(w & 255u);
      }
      const float* gl = g_Glab + (long)pb * G3_;
      f32x4 glab[3];
      #pragma unroll
      for (int g = 0; g < 3; ++g)
        glab[g] = *(const f32x4*)&gl[g * HID_ + jbase];

      __syncthreads();  // protect sCp
      #pragma unroll
      for (int rt = 0; rt < 3; ++rt)
        #pragma unroll
        for (int bt = 0; bt < 4; ++bt)
          *(f32x4*)&sCp[(wv * 64 + bt * 16 + m) * CP_STRIDE + rt * 16 + q * 4] =
              acc[rt][bt];
      __syncthreads();
      #pragma unroll
      for (int g = 0; g < 3; ++g) {
        f32x4 sv = f32x4{0.f, 0.f, 0.f, 0.f};
        #pragma unroll
        for (int w = 0; w < 4; ++w)
          sv += *(const f32x4*)&sCp[(w * 64 + bl) * CP_STRIDE + g * 16 + jj];
        sred[g] = sv;
      }

      // ---- gate epilogue: h_new for (bglob, jbase..jbase+3) ----
      u16x4 whi, wlo;
      f32x4 hf;
      #pragma unroll
      for (int t4 = 0; t4 < 4; ++t4) {
        float ghr = sred[0][t4] + bhh[0][t4];
        float ghz = sred[1][t4] + bhh[1][t4];
        float ghn = sred[2][t4] + bhh[2][t4];
        float gir = gixp[0][t4] + glab[0][t4];   // b_ih folded into G_lab
        float giz = gixp[1][t4] + glab[1][t4];
        float gin = gixp[2][t4] + glab[2][t4];
        float r = 1.f / (1.f + expf(-(gir + ghr)));
        float z = 1.f / (1.f + expf(-(giz + ghz)));
        float n = tanhf(gin + r * ghn);   // b_hh_n inside r*(...) per PyTorch
        float hn = (1.f - z) * n + z * hreg[t4];
        hreg[t4] = hn;
        hf[t4] = hn;
        unsigned short uhi = f2bf(hn);
        whi[t4] = uhi;
        wlo[t4] = f2bf(hn - bf2f(uhi));
      }
      // ---- PLAIN stores; release fence + stamp publish below ----
      *(u16x4*)&g_hhi[wb][(long)bglob * HID_ + jbase] = whi;
      *(u16x4*)&g_hlo[wb][(long)bglob * HID_ + jbase] = wlo;
      *(f32x4*)&g_hf32[wb][(long)bglob * HID_ + jbase] = hf;

      asm volatile("s_waitcnt vmcnt(0)" ::: "memory");  // stores in L2
      __syncthreads();                                  // all threads done
      if (tid == 0) {
        __builtin_amdgcn_fence(__ATOMIC_RELEASE, "agent");  // buffer_wbl2
        ast32(&g_hseq[bg][rg * 16], (unsigned)(it + 1));
      }
    }
  }
}

extern "C" void kernel_launch(void* const* d_in, const int* in_sizes, int n_in,
                              void* d_out, int out_size, void* d_ws, size_t ws_size,
                              hipStream_t stream) {
  const void* hs    = d_in[0];
  const void* emb   = d_in[1];
  const void* W_ih  = d_in[2];
  const void* W_hh  = d_in[3];
  const void* b_ih  = d_in[4];
  const void* b_hh  = d_in[5];
  const void* W_out = d_in[6];
  const void* b_out = d_in[7];

  hipLaunchKernelGGL(k_zero, dim3(256), dim3(256), 0, stream);
  hipLaunchKernelGGL(k_detect, dim3(1), dim3(64), 0, stream,
                     (const unsigned short*)W_ih);
  hipLaunchKernelGGL(k_prep, dim3(32 * 12), dim3(256), 0, stream,
                     emb, W_ih, b_ih);
  hipLaunchKernelGGL(k_prepw, dim3(3072), dim3(256), 0, stream, W_ih, W_hh);
  hipFuncSetAttribute((const void*)k_gix,
                      hipFuncAttributeMaxDynamicSharedMemorySize, LDS_BYTES);
  hipFuncSetAttribute((const void*)k_loop,
                      hipFuncAttributeMaxDynamicSharedMemorySize, LDS_BYTES);
  hipLaunchKernelGGL(k_gix, dim3(256), dim3(256), LDS_BYTES, stream, hs, W_ih);
  hipLaunchKernelGGL(k_loop, dim3(256), dim3(256), LDS_BYTES, stream,
                     W_hh, b_hh, W_out, b_out, d_out);
}